// Round 9
// baseline (279.083 us; speedup 1.0000x reference)
//
#include <hip/hip_runtime.h>

typedef __attribute__((ext_vector_type(8))) short bf16x8;
typedef __attribute__((ext_vector_type(4))) float f32x4;

#define DEVICE __device__ __forceinline__

static constexpr int Tc = 2048;     // seq len
static constexpr int Dc = 2048;     // model dim
static constexpr int Hc = 16;       // heads
static constexpr int HD = 128;      // head dim
static constexpr int MR = 4096;     // B*T rows
static constexpr int NQKV = 6144;   // 3*D

DEVICE float bf2f(unsigned short u) {
  unsigned int t = ((unsigned int)u) << 16;
  float f; __builtin_memcpy(&f, &t, 4); return f;
}
DEVICE unsigned short f2bf(float f) {
  unsigned int t; __builtin_memcpy(&t, &f, 4);
  unsigned int r = (t + 0x7fffu + ((t >> 16) & 1u)) >> 16;
  return (unsigned short)r;
}

DEVICE void async_cp16(const void* g, void* lds) {
  __builtin_amdgcn_global_load_lds((const __attribute__((address_space(1))) void*)g,
                                   (__attribute__((address_space(3))) void*)lds, 16, 0, 0);
}

// epilogue LDS tile swizzle: row t (256B rows), byte col d2; bijective per row,
// spreads both row-major 16B reads and col-major scalar reads across banks.
DEVICE int lsw(int t, int d2) {
  return t * 256 + (d2 ^ ((((t & 7) ^ ((t >> 3) & 7)) << 4)));
}

// ---------------- RoPE cos/sin table: cs[t][j] = (cos, sin), j in [0,64) ----
__global__ void rope_table_kernel(float2* cs) {
  int t = blockIdx.x;
  int j = threadIdx.x;                   // 0..63
  float inv = powf(10000.0f, -(float)(2 * j) / 128.0f);
  float ang = (float)t * inv;
  cs[t * 64 + j] = make_float2(cosf(ang), sinf(ang));
}

// ---------------- fp32 -> bf16 elementwise (vectorized) ---------------------
__global__ void f32_to_bf16_kernel(const float* __restrict__ in,
                                   unsigned short* __restrict__ out, int n) {
  int i = (blockIdx.x * blockDim.x + threadIdx.x) * 4;
  if (i >= n) return;
  float4 v = *(const float4*)(in + i);
  ushort4 o;
  o.x = f2bf(v.x); o.y = f2bf(v.y); o.z = f2bf(v.z); o.w = f2bf(v.w);
  *(ushort4*)(out + i) = o;
}

// ------------- transpose fp32 (R x C) -> bf16 (C x R), 64x64 tiles ---------
__global__ __launch_bounds__(256)
void transpose_f32_bf16_kernel(const float* __restrict__ in,
                               unsigned short* __restrict__ out,
                               int R, int C) {
  __shared__ float tile[64][68];
  int c0 = blockIdx.x * 64, r0 = blockIdx.y * 64;
  int tid = threadIdx.x;
#pragma unroll
  for (int it = 0; it < 4; ++it) {
    int idx = it * 256 + tid;        // 0..1023
    int r = idx >> 4;                // 0..63
    int c = (idx & 15) * 4;          // 0..60
    float4 v = *(const float4*)&in[(size_t)(r0 + r) * C + c0 + c];
    tile[r][c] = v.x; tile[r][c + 1] = v.y;
    tile[r][c + 2] = v.z; tile[r][c + 3] = v.w;
  }
  __syncthreads();
#pragma unroll
  for (int it = 0; it < 2; ++it) {
    int idx = it * 256 + tid;        // 0..511
    int r = idx >> 3;                // out row (c-dim) 0..63
    int c = (idx & 7) * 8;           // out col base (r-dim)
    bf16x8 ov;
#pragma unroll
    for (int i = 0; i < 8; ++i) ov[i] = (short)f2bf(tile[c + i][r]);
    *(bf16x8*)&out[(size_t)(c0 + r) * R + r0 + c] = ov;
  }
}

// ========== QKV GEMM with fused RoPE + head-split + V-transpose ============
__global__ __launch_bounds__(256, 2)
void gemm_qkv_kernel(const unsigned short* __restrict__ A,
                     const unsigned short* __restrict__ Bt,
                     const float2* __restrict__ cs,
                     unsigned short* __restrict__ qh,
                     unsigned short* __restrict__ kh,
                     unsigned short* __restrict__ vt) {
  const int N = NQKV, K = Dc;
  __shared__ __align__(16) unsigned short sh[128 * 128];   // 32KB
  unsigned short* As = sh;               // [128*64] main-loop A tile
  unsigned short* Bs = sh + 128 * 64;    // [128*64] main-loop B tile

  int nbx = N >> 7;                      // 48
  int nwg = gridDim.x;                   // 1536
  int wg = blockIdx.x;
  int cpx = nwg >> 3;
  wg = (wg & 7) * cpx + (wg >> 3);       // XCD-contiguous (bijective: nwg%8==0)
  int gsize = nbx * 8;                   // GROUP_M=8 supertiles for L2 reuse
  int g = wg / gsize, rem = wg - g * gsize;
  int by = g * 8 + (rem & 7), bx = rem >> 3;
  int m0 = by << 7, n0 = bx << 7;

  int tid = threadIdx.x, lane = tid & 63, wid = tid >> 6;
  int wm = (wid >> 1) << 6, wn = (wid & 1) << 6;

  f32x4 acc[4][4] = {};

  for (int k0 = 0; k0 < K; k0 += 64) {
    __syncthreads();
#pragma unroll
    for (int r = 0; r < 4; ++r) {
      int p = r * 4096 + wid * 1024 + lane * 16;   // byte offset in tile
      int row = p >> 7;
      int cb = (p & 127) ^ ((row & 7) << 4);       // pre-swizzled source col
      const char* ga = (const char*)A + ((size_t)(m0 + row) * K + k0) * 2 + cb;
      async_cp16(ga, (char*)As + r * 4096 + wid * 1024);
      const char* gb = (const char*)Bt + ((size_t)(n0 + row) * K + k0) * 2 + cb;
      async_cp16(gb, (char*)Bs + r * 4096 + wid * 1024);
    }
    __syncthreads();

#pragma unroll
    for (int ks = 0; ks < 2; ++ks) {
      bf16x8 af[4], bfr[4];
#pragma unroll
      for (int mi = 0; mi < 4; ++mi) {
        int row = wm + mi * 16 + (lane & 15);
        int cb = (ks * 64 + ((lane >> 4) << 4)) ^ ((row & 7) << 4);
        af[mi] = *(const bf16x8*)((const char*)As + row * 128 + cb);
      }
#pragma unroll
      for (int ni = 0; ni < 4; ++ni) {
        int row = wn + ni * 16 + (lane & 15);
        int cb = (ks * 64 + ((lane >> 4) << 4)) ^ ((row & 7) << 4);
        bfr[ni] = *(const bf16x8*)((const char*)Bs + row * 128 + cb);
      }
#pragma unroll
      for (int mi = 0; mi < 4; ++mi)
#pragma unroll
        for (int ni = 0; ni < 4; ++ni)
          acc[mi][ni] = __builtin_amdgcn_mfma_f32_16x16x32_bf16(
              af[mi], bfr[ni], acc[mi][ni], 0, 0, 0);
    }
  }

  // ---- epilogue: acc -> LDS (bf16, swizzled) ----
  __syncthreads();   // all waves done reading As/Bs
#pragma unroll
  for (int mi = 0; mi < 4; ++mi)
#pragma unroll
    for (int ni = 0; ni < 4; ++ni)
#pragma unroll
      for (int r = 0; r < 4; ++r) {
        int t_ = wm + mi * 16 + ((lane >> 4) << 2) + r;
        int d_ = wn + ni * 16 + (lane & 15);
        *(unsigned short*)((char*)sh + lsw(t_, d_ * 2)) = f2bf(acc[mi][ni][r]);
      }
  __syncthreads();

  int sector = n0 >> 11;                 // 0=Q, 1=K, 2=V
  int h = (n0 & 2047) >> 7;
  if (sector < 2) {
    unsigned short* dst = sector ? kh : qh;
#pragma unroll
    for (int it = 0; it < 4; ++it) {
      int idx = it * 256 + tid;
      int r = idx >> 3, j0 = (idx & 7) * 8;
      int m = m0 + r;
      int t = m & (Tc - 1), b = m >> 11;
      bf16x8 o1, o2;
#pragma unroll
      for (int i = 0; i < 8; ++i) {
        float q1 = bf2f(*(const unsigned short*)((const char*)sh + lsw(r, (j0 + i) * 2)));
        float q2 = bf2f(*(const unsigned short*)((const char*)sh + lsw(r, (j0 + i + 64) * 2)));
        float2 c = cs[t * 64 + j0 + i];
        o1[i] = (short)f2bf(q1 * c.x - q2 * c.y);
        o2[i] = (short)f2bf(q2 * c.x + q1 * c.y);
      }
      size_t ob = ((size_t)(b * Hc + h) * Tc + t) * HD;
      *(bf16x8*)(dst + ob + j0) = o1;
      *(bf16x8*)(dst + ob + 64 + j0) = o2;
    }
  } else {
    int bh = (m0 >> 11) * Hc + h;
    int tb = m0 & (Tc - 1);
#pragma unroll
    for (int it = 0; it < 8; ++it) {
      int idx = it * 256 + tid;
      int d = idx >> 4, tc = idx & 15;
      bf16x8 o;
#pragma unroll
      for (int i = 0; i < 8; ++i)
        o[i] = (short)*(const unsigned short*)((const char*)sh + lsw(tc * 8 + i, d * 2));
      *(bf16x8*)(vt + (size_t)(bh * HD + d) * Tc + tb + tc * 8) = o;
    }
  }
}

// ---------------- 128x128 bf16 GEMM (m97 structure), for out-proj -----------
__global__ __launch_bounds__(256, 2)
void gemm_bt_kernel(const unsigned short* __restrict__ A,
                    const unsigned short* __restrict__ Bt,
                    float* __restrict__ C, int M, int N, int K) {
  __shared__ unsigned short As[128 * 64];
  __shared__ unsigned short Bs[128 * 64];

  int nbx = N >> 7;
  int nwg = gridDim.x;
  int wg = blockIdx.x;
  int cpx = nwg >> 3;
  wg = (wg & 7) * cpx + (wg >> 3);
  int gsize = nbx * 8;
  int g = wg / gsize, rem = wg - g * gsize;
  int by = g * 8 + (rem & 7), bx = rem >> 3;
  int m0 = by << 7, n0 = bx << 7;

  int tid = threadIdx.x, lane = tid & 63, wid = tid >> 6;
  int wm = (wid >> 1) << 6, wn = (wid & 1) << 6;

  f32x4 acc[4][4] = {};

  for (int k0 = 0; k0 < K; k0 += 64) {
    __syncthreads();
#pragma unroll
    for (int r = 0; r < 4; ++r) {
      int p = r * 4096 + wid * 1024 + lane * 16;
      int row = p >> 7;
      int cb = (p & 127) ^ ((row & 7) << 4);
      const char* ga = (const char*)A + ((size_t)(m0 + row) * K + k0) * 2 + cb;
      async_cp16(ga, (char*)As + r * 4096 + wid * 1024);
      const char* gb = (const char*)Bt + ((size_t)(n0 + row) * K + k0) * 2 + cb;
      async_cp16(gb, (char*)Bs + r * 4096 + wid * 1024);
    }
    __syncthreads();

#pragma unroll
    for (int ks = 0; ks < 2; ++ks) {
      bf16x8 af[4], bfr[4];
#pragma unroll
      for (int mi = 0; mi < 4; ++mi) {
        int row = wm + mi * 16 + (lane & 15);
        int cb = (ks * 64 + ((lane >> 4) << 4)) ^ ((row & 7) << 4);
        af[mi] = *(const bf16x8*)((const char*)As + row * 128 + cb);
      }
#pragma unroll
      for (int ni = 0; ni < 4; ++ni) {
        int row = wn + ni * 16 + (lane & 15);
        int cb = (ks * 64 + ((lane >> 4) << 4)) ^ ((row & 7) << 4);
        bfr[ni] = *(const bf16x8*)((const char*)Bs + row * 128 + cb);
      }
#pragma unroll
      for (int mi = 0; mi < 4; ++mi)
#pragma unroll
        for (int ni = 0; ni < 4; ++ni)
          acc[mi][ni] = __builtin_amdgcn_mfma_f32_16x16x32_bf16(
              af[mi], bfr[ni], acc[mi][ni], 0, 0, 0);
    }
  }

#pragma unroll
  for (int mi = 0; mi < 4; ++mi)
#pragma unroll
    for (int ni = 0; ni < 4; ++ni)
#pragma unroll
      for (int r = 0; r < 4; ++r) {
        int row = m0 + wm + mi * 16 + ((lane >> 4) << 2) + r;
        int col = n0 + wn + ni * 16 + (lane & 15);
        C[(size_t)row * N + col] = acc[mi][ni][r];
      }
}

// ---------------- causal flash attention ------------------------------------
// BQ=128, 16 q-tiles paired (p, 15-p) -> uniform 34 k-tiles per block.
// grid (bh=32, pairp=8): blocks sharing (b,h) -> same XCD -> K/V L2-shared.
// 4 waves x 32 q-rows each (halves the 8x-redundant K/V LDS reads per MFMA).
// Triple-buffered K/V staging, counted vmcnt, 2-deep prefetch.
__global__ __launch_bounds__(256, 1)
void attn_kernel(const unsigned short* __restrict__ qh,
                 const unsigned short* __restrict__ kh,
                 const unsigned short* __restrict__ vt,
                 unsigned short* __restrict__ ao) {
  const float SCL2 = 0.08838834764831845f * 1.4426950408889634f;  // scale*log2e
  int bh = blockIdx.x;                       // 0..31
  int pairp = blockIdx.y;                    // 0..7
  int b = bh >> 4, h = bh & 15;

  __shared__ unsigned short Ks[3][64 * 128];   // 3 x 16KB, 256B rows, swizzled
  __shared__ unsigned short Vs[3][128 * 64];   // 3 x 16KB, V^T rows=d, 128B
  __shared__ unsigned short Ps[4][32 * 64];    // 16KB, per-wave P, 128B rows

  int tid = threadIdx.x, lane = tid & 63, wid = tid >> 6;

  const unsigned short* Kg = kh + (size_t)bh * Tc * HD;
  const unsigned short* Vg = vt + (size_t)bh * HD * Tc;

  auto stage = [&](int kt, int buf) {        // 8 vmem loads per thread
#pragma unroll
    for (int r = 0; r < 4; ++r) {
      int p = r * 4096 + tid * 16;
      {
        int row = p >> 8, cb = p & 255;
        const char* g = (const char*)Kg + ((size_t)(kt * 64 + row)) * 256 +
                        (cb ^ ((row & 7) << 4));
        async_cp16(g, (char*)&Ks[buf][0] + (p & ~15));
      }
      {
        int d = p >> 7, cb = p & 127;
        const char* g = (const char*)Vg + (size_t)d * (Tc * 2) + kt * 128 +
                        (cb ^ ((d & 7) << 4));
        async_cp16(g, (char*)&Vs[buf][0] + (p & ~15));
      }
    }
  };

#pragma unroll 1
  for (int pass = 0; pass < 2; ++pass) {
    int qt = pass ? (15 - pairp) : pairp;
    const unsigned short* Qg = qh + ((size_t)bh * Tc + qt * 128) * HD;

    // Q fragments direct from global; drain so loop vmcnt counts stay exact
    bf16x8 qf[2][4];
#pragma unroll
    for (int mi = 0; mi < 2; ++mi)
#pragma unroll
      for (int ks = 0; ks < 4; ++ks) {
        int row = wid * 32 + mi * 16 + (lane & 15);
        qf[mi][ks] = *(const bf16x8*)((const char*)Qg + row * 256 + ks * 64 +
                                      ((lane >> 4) << 4));
      }
    asm volatile("s_waitcnt vmcnt(0)" ::: "memory");

    f32x4 oacc[2][8] = {};
    float mrow[2][4], lrow[2][4];
#pragma unroll
    for (int mi = 0; mi < 2; ++mi)
#pragma unroll
      for (int r = 0; r < 4; ++r) { mrow[mi][r] = -1e30f; lrow[mi][r] = 0.f; }

    int nkt = 2 * (qt + 1);
    __syncthreads();     // pass boundary: prior pass's LDS reads done
    stage(0, 0);
    stage(1, 1);         // nkt >= 2 always
#pragma unroll 1
    for (int kt = 0; kt < nkt; ++kt) {
      // wait for tile kt (own loads), then barrier -> all threads' loads done
      if (kt + 1 < nkt)
        asm volatile("s_waitcnt vmcnt(8)" ::: "memory");
      else
        asm volatile("s_waitcnt vmcnt(0)" ::: "memory");
      asm volatile("s_barrier" ::: "memory");
      if (kt + 2 < nkt) stage(kt + 2, (kt + 2) % 3);
      int cur = kt % 3;

      // S = Q K^T  (32 x 64): kf shared across both mi halves
      f32x4 sacc[2][4] = {};
      __builtin_amdgcn_s_setprio(1);
#pragma unroll
      for (int ks = 0; ks < 4; ++ks) {
#pragma unroll
        for (int ni = 0; ni < 4; ++ni) {
          int row = ni * 16 + (lane & 15);
          int cb = (ks * 64 + ((lane >> 4) << 4)) ^ ((row & 7) << 4);
          bf16x8 kf = *(const bf16x8*)((const char*)&Ks[cur][0] + row * 256 + cb);
#pragma unroll
          for (int mi = 0; mi < 2; ++mi)
            sacc[mi][ni] = __builtin_amdgcn_mfma_f32_16x16x32_bf16(
                qf[mi][ks], kf, sacc[mi][ni], 0, 0, 0);
        }
      }
      __builtin_amdgcn_s_setprio(0);

      // softmax in exp2 domain; defer max & sum (steady path: no cross-lane)
      bool diag = (kt >= 2 * qt);
      float sv[2][4][4];           // [mi][ni][r]
      float pmax[2][4];
      bool allok = true;
#pragma unroll
      for (int mi = 0; mi < 2; ++mi)
#pragma unroll
        for (int r = 0; r < 4; ++r) {
          int qrow = qt * 128 + wid * 32 + mi * 16 + ((lane >> 4) << 2) + r;
          float mx = -1e30f;
#pragma unroll
          for (int ni = 0; ni < 4; ++ni) {
            float s = sacc[mi][ni][r] * SCL2;
            if (diag) {
              int kcol = kt * 64 + ni * 16 + (lane & 15);
              if (kcol > qrow) s = -1e30f;
            }
            sv[mi][ni][r] = s;
            mx = fmaxf(mx, s);
          }
          pmax[mi][r] = mx;
          allok = allok && (mx <= mrow[mi][r] + 8.f);
        }
      if (!__all(allok)) {         // rare: running max moved -> reduce+rescale
#pragma unroll
        for (int mi = 0; mi < 2; ++mi)
#pragma unroll
          for (int r = 0; r < 4; ++r) {
            float gm = pmax[mi][r];
            gm = fmaxf(gm, __shfl_xor(gm, 1));
            gm = fmaxf(gm, __shfl_xor(gm, 2));
            gm = fmaxf(gm, __shfl_xor(gm, 4));
            gm = fmaxf(gm, __shfl_xor(gm, 8));
            float mnew = fmaxf(mrow[mi][r], gm);
            float fsc = exp2f(mrow[mi][r] - mnew);
            mrow[mi][r] = mnew;
            lrow[mi][r] *= fsc;
#pragma unroll
            for (int nj = 0; nj < 8; ++nj) oacc[mi][nj][r] *= fsc;
          }
      }

      // P = exp2(sv - m); per-lane partial sums; write P (bf16) to LDS
#pragma unroll
      for (int mi = 0; mi < 2; ++mi)
#pragma unroll
        for (int ni = 0; ni < 4; ++ni)
#pragma unroll
          for (int r = 0; r < 4; ++r) {
            float pp = exp2f(sv[mi][ni][r] - mrow[mi][r]);
            lrow[mi][r] += pp;
            int row = mi * 16 + ((lane >> 4) << 2) + r;
            int colb = (ni * 16 + (lane & 15)) * 2;
            *(unsigned short*)((char*)&Ps[wid][0] + row * 128 +
                               (colb ^ ((row & 7) << 4))) = f2bf(pp);
          }

      // O += P @ V  (vf shared across both mi halves)
      __builtin_amdgcn_s_setprio(1);
#pragma unroll
      for (int ks = 0; ks < 2; ++ks) {
        bf16x8 pf[2];
#pragma unroll
        for (int mi = 0; mi < 2; ++mi) {
          int prow = mi * 16 + (lane & 15);
          int pcb = (ks * 64 + ((lane >> 4) << 4)) ^ ((prow & 7) << 4);
          pf[mi] = *(const bf16x8*)((const char*)&Ps[wid][0] + prow * 128 + pcb);
        }
#pragma unroll
        for (int nj = 0; nj < 8; ++nj) {
          int vrow = nj * 16 + (lane & 15);
          int vcb = (ks * 64 + ((lane >> 4) << 4)) ^ ((vrow & 7) << 4);
          bf16x8 vf = *(const bf16x8*)((const char*)&Vs[cur][0] + vrow * 128 + vcb);
#pragma unroll
          for (int mi = 0; mi < 2; ++mi)
            oacc[mi][nj] = __builtin_amdgcn_mfma_f32_16x16x32_bf16(
                pf[mi], vf, oacc[mi][nj], 0, 0, 0);
        }
      }
      __builtin_amdgcn_s_setprio(0);
    }

    // epilogue: reduce deferred row sums across 16-lane groups, normalize
#pragma unroll
    for (int mi = 0; mi < 2; ++mi) {
      float inv[4];
#pragma unroll
      for (int r = 0; r < 4; ++r) {
        float s = lrow[mi][r];
        s += __shfl_xor(s, 1);
        s += __shfl_xor(s, 2);
        s += __shfl_xor(s, 4);
        s += __shfl_xor(s, 8);
        inv[r] = 1.f / s;
      }
#pragma unroll
      for (int nj = 0; nj < 8; ++nj)
#pragma unroll
        for (int r = 0; r < 4; ++r) {
          int trow = qt * 128 + wid * 32 + mi * 16 + ((lane >> 4) << 2) + r;
          int col = nj * 16 + (lane & 15);
          ao[((size_t)(b * Tc + trow)) * Dc + h * HD + col] =
              f2bf(oacc[mi][nj][r] * inv[r]);
        }
    }
  }
}

// ---------------- launcher --------------------------------------------------
extern "C" void kernel_launch(void* const* d_in, const int* in_sizes, int n_in,
                              void* d_out, int out_size, void* d_ws,
                              size_t ws_size, hipStream_t stream) {
  const float* x = (const float*)d_in[0];
  const float* w_qkv = (const float*)d_in[1];
  const float* w_out = (const float*)d_in[2];
  float* out = (float*)d_out;

  char* ws = (char*)d_ws;
  size_t off = 0;
  auto alloc = [&](size_t bytes) {
    char* p = ws + off;
    off += (bytes + 255) & ~(size_t)255;
    return p;
  };
  unsigned short* xb    = (unsigned short*)alloc((size_t)MR * Dc * 2);
  unsigned short* wqkvT = (unsigned short*)alloc((size_t)NQKV * Dc * 2);
  unsigned short* woutT = (unsigned short*)alloc((size_t)Dc * Dc * 2);
  unsigned short* qhp   = (unsigned short*)alloc((size_t)MR * Dc * 2);
  unsigned short* khp   = (unsigned short*)alloc((size_t)MR * Dc * 2);
  unsigned short* vtp   = (unsigned short*)alloc((size_t)MR * Dc * 2);
  unsigned short* aop   = (unsigned short*)alloc((size_t)MR * Dc * 2);
  float2* cs            = (float2*)alloc((size_t)Tc * 64 * sizeof(float2));

  rope_table_kernel<<<Tc, 64, 0, stream>>>(cs);
  f32_to_bf16_kernel<<<(MR * Dc / 4 + 255) / 256, 256, 0, stream>>>(x, xb, MR * Dc);
  transpose_f32_bf16_kernel<<<dim3(NQKV / 64, Dc / 64), 256, 0, stream>>>(
      w_qkv, wqkvT, Dc, NQKV);
  transpose_f32_bf16_kernel<<<dim3(Dc / 64, Dc / 64), 256, 0, stream>>>(
      w_out, woutT, Dc, Dc);
  gemm_qkv_kernel<<<(MR / 128) * (NQKV / 128), 256, 0, stream>>>(
      xb, wqkvT, cs, qhp, khp, vtp);
  attn_kernel<<<dim3(32, 8), 256, 0, stream>>>(qhp, khp, vtp, aop);
  gemm_bt_kernel<<<(MR / 128) * (Dc / 128), 256, 0, stream>>>(
      aop, woutT, out, MR, Dc, Dc);
}

// Round 10
// 249.968 us; speedup vs baseline: 1.1165x; 1.1165x over previous
//
#include <hip/hip_runtime.h>

typedef __attribute__((ext_vector_type(8))) short bf16x8;
typedef __attribute__((ext_vector_type(4))) float f32x4;

#define DEVICE __device__ __forceinline__

static constexpr int Tc = 2048;     // seq len
static constexpr int Dc = 2048;     // model dim
static constexpr int Hc = 16;       // heads
static constexpr int HD = 128;      // head dim
static constexpr int MR = 4096;     // B*T rows
static constexpr int NQKV = 6144;   // 3*D

DEVICE float bf2f(unsigned short u) {
  unsigned int t = ((unsigned int)u) << 16;
  float f; __builtin_memcpy(&f, &t, 4); return f;
}
DEVICE unsigned short f2bf(float f) {
  unsigned int t; __builtin_memcpy(&t, &f, 4);
  unsigned int r = (t + 0x7fffu + ((t >> 16) & 1u)) >> 16;
  return (unsigned short)r;
}

DEVICE void async_cp16(const void* g, void* lds) {
  __builtin_amdgcn_global_load_lds((const __attribute__((address_space(1))) void*)g,
                                   (__attribute__((address_space(3))) void*)lds, 16, 0, 0);
}

// epilogue LDS tile swizzle: row t (256B rows), byte col d2; bijective per row,
// spreads both row-major 16B reads and col-major scalar reads across banks.
DEVICE int lsw(int t, int d2) {
  return t * 256 + (d2 ^ ((((t & 7) ^ ((t >> 3) & 7)) << 4)));
}

// ---------------- RoPE cos/sin table: cs[t][j] = (cos, sin), j in [0,64) ----
__global__ void rope_table_kernel(float2* cs) {
  int t = blockIdx.x;
  int j = threadIdx.x;                   // 0..63
  float inv = powf(10000.0f, -(float)(2 * j) / 128.0f);
  float ang = (float)t * inv;
  cs[t * 64 + j] = make_float2(cosf(ang), sinf(ang));
}

// ---------------- fp32 -> bf16 elementwise (vectorized) ---------------------
__global__ void f32_to_bf16_kernel(const float* __restrict__ in,
                                   unsigned short* __restrict__ out, int n) {
  int i = (blockIdx.x * blockDim.x + threadIdx.x) * 4;
  if (i >= n) return;
  float4 v = *(const float4*)(in + i);
  ushort4 o;
  o.x = f2bf(v.x); o.y = f2bf(v.y); o.z = f2bf(v.z); o.w = f2bf(v.w);
  *(ushort4*)(out + i) = o;
}

// ------------- transpose fp32 (R x C) -> bf16 (C x R), 64x64 tiles ---------
__global__ __launch_bounds__(256)
void transpose_f32_bf16_kernel(const float* __restrict__ in,
                               unsigned short* __restrict__ out,
                               int R, int C) {
  __shared__ float tile[64][68];
  int c0 = blockIdx.x * 64, r0 = blockIdx.y * 64;
  int tid = threadIdx.x;
#pragma unroll
  for (int it = 0; it < 4; ++it) {
    int idx = it * 256 + tid;        // 0..1023
    int r = idx >> 4;                // 0..63
    int c = (idx & 15) * 4;          // 0..60
    float4 v = *(const float4*)&in[(size_t)(r0 + r) * C + c0 + c];
    tile[r][c] = v.x; tile[r][c + 1] = v.y;
    tile[r][c + 2] = v.z; tile[r][c + 3] = v.w;
  }
  __syncthreads();
#pragma unroll
  for (int it = 0; it < 2; ++it) {
    int idx = it * 256 + tid;        // 0..511
    int r = idx >> 3;                // out row (c-dim) 0..63
    int c = (idx & 7) * 8;           // out col base (r-dim)
    bf16x8 ov;
#pragma unroll
    for (int i = 0; i < 8; ++i) ov[i] = (short)f2bf(tile[c + i][r]);
    *(bf16x8*)&out[(size_t)(c0 + r) * R + r0 + c] = ov;
  }
}

// ========== QKV GEMM with fused RoPE + head-split + V-transpose ============
__global__ __launch_bounds__(256, 2)
void gemm_qkv_kernel(const unsigned short* __restrict__ A,
                     const unsigned short* __restrict__ Bt,
                     const float2* __restrict__ cs,
                     unsigned short* __restrict__ qh,
                     unsigned short* __restrict__ kh,
                     unsigned short* __restrict__ vt) {
  const int N = NQKV, K = Dc;
  __shared__ __align__(16) unsigned short sh[128 * 128];   // 32KB
  unsigned short* As = sh;               // [128*64] main-loop A tile
  unsigned short* Bs = sh + 128 * 64;    // [128*64] main-loop B tile

  int nbx = N >> 7;                      // 48
  int nwg = gridDim.x;                   // 1536
  int wg = blockIdx.x;
  int cpx = nwg >> 3;
  wg = (wg & 7) * cpx + (wg >> 3);       // XCD-contiguous (bijective: nwg%8==0)
  int gsize = nbx * 8;                   // GROUP_M=8 supertiles for L2 reuse
  int g = wg / gsize, rem = wg - g * gsize;
  int by = g * 8 + (rem & 7), bx = rem >> 3;
  int m0 = by << 7, n0 = bx << 7;

  int tid = threadIdx.x, lane = tid & 63, wid = tid >> 6;
  int wm = (wid >> 1) << 6, wn = (wid & 1) << 6;

  f32x4 acc[4][4] = {};

  for (int k0 = 0; k0 < K; k0 += 64) {
    __syncthreads();
#pragma unroll
    for (int r = 0; r < 4; ++r) {
      int p = r * 4096 + wid * 1024 + lane * 16;   // byte offset in tile
      int row = p >> 7;
      int cb = (p & 127) ^ ((row & 7) << 4);       // pre-swizzled source col
      const char* ga = (const char*)A + ((size_t)(m0 + row) * K + k0) * 2 + cb;
      async_cp16(ga, (char*)As + r * 4096 + wid * 1024);
      const char* gb = (const char*)Bt + ((size_t)(n0 + row) * K + k0) * 2 + cb;
      async_cp16(gb, (char*)Bs + r * 4096 + wid * 1024);
    }
    __syncthreads();

#pragma unroll
    for (int ks = 0; ks < 2; ++ks) {
      bf16x8 af[4], bfr[4];
#pragma unroll
      for (int mi = 0; mi < 4; ++mi) {
        int row = wm + mi * 16 + (lane & 15);
        int cb = (ks * 64 + ((lane >> 4) << 4)) ^ ((row & 7) << 4);
        af[mi] = *(const bf16x8*)((const char*)As + row * 128 + cb);
      }
#pragma unroll
      for (int ni = 0; ni < 4; ++ni) {
        int row = wn + ni * 16 + (lane & 15);
        int cb = (ks * 64 + ((lane >> 4) << 4)) ^ ((row & 7) << 4);
        bfr[ni] = *(const bf16x8*)((const char*)Bs + row * 128 + cb);
      }
#pragma unroll
      for (int mi = 0; mi < 4; ++mi)
#pragma unroll
        for (int ni = 0; ni < 4; ++ni)
          acc[mi][ni] = __builtin_amdgcn_mfma_f32_16x16x32_bf16(
              af[mi], bfr[ni], acc[mi][ni], 0, 0, 0);
    }
  }

  // ---- epilogue: acc -> LDS (bf16, swizzled) ----
  __syncthreads();   // all waves done reading As/Bs
#pragma unroll
  for (int mi = 0; mi < 4; ++mi)
#pragma unroll
    for (int ni = 0; ni < 4; ++ni)
#pragma unroll
      for (int r = 0; r < 4; ++r) {
        int t_ = wm + mi * 16 + ((lane >> 4) << 2) + r;
        int d_ = wn + ni * 16 + (lane & 15);
        *(unsigned short*)((char*)sh + lsw(t_, d_ * 2)) = f2bf(acc[mi][ni][r]);
      }
  __syncthreads();

  int sector = n0 >> 11;                 // 0=Q, 1=K, 2=V
  int h = (n0 & 2047) >> 7;
  if (sector < 2) {
    unsigned short* dst = sector ? kh : qh;
#pragma unroll
    for (int it = 0; it < 4; ++it) {
      int idx = it * 256 + tid;
      int r = idx >> 3, j0 = (idx & 7) * 8;
      int m = m0 + r;
      int t = m & (Tc - 1), b = m >> 11;
      bf16x8 o1, o2;
#pragma unroll
      for (int i = 0; i < 8; ++i) {
        float q1 = bf2f(*(const unsigned short*)((const char*)sh + lsw(r, (j0 + i) * 2)));
        float q2 = bf2f(*(const unsigned short*)((const char*)sh + lsw(r, (j0 + i + 64) * 2)));
        float2 c = cs[t * 64 + j0 + i];
        o1[i] = (short)f2bf(q1 * c.x - q2 * c.y);
        o2[i] = (short)f2bf(q2 * c.x + q1 * c.y);
      }
      size_t ob = ((size_t)(b * Hc + h) * Tc + t) * HD;
      *(bf16x8*)(dst + ob + j0) = o1;
      *(bf16x8*)(dst + ob + 64 + j0) = o2;
    }
  } else {
    int bh = (m0 >> 11) * Hc + h;
    int tb = m0 & (Tc - 1);
#pragma unroll
    for (int it = 0; it < 8; ++it) {
      int idx = it * 256 + tid;
      int d = idx >> 4, tc = idx & 15;
      bf16x8 o;
#pragma unroll
      for (int i = 0; i < 8; ++i)
        o[i] = (short)*(const unsigned short*)((const char*)sh + lsw(tc * 8 + i, d * 2));
      *(bf16x8*)(vt + (size_t)(bh * HD + d) * Tc + tb + tc * 8) = o;
    }
  }
}

// ---------------- 128x128 bf16 GEMM (m97 structure), for out-proj -----------
__global__ __launch_bounds__(256, 2)
void gemm_bt_kernel(const unsigned short* __restrict__ A,
                    const unsigned short* __restrict__ Bt,
                    float* __restrict__ C, int M, int N, int K) {
  __shared__ unsigned short As[128 * 64];
  __shared__ unsigned short Bs[128 * 64];

  int nbx = N >> 7;
  int nwg = gridDim.x;
  int wg = blockIdx.x;
  int cpx = nwg >> 3;
  wg = (wg & 7) * cpx + (wg >> 3);
  int gsize = nbx * 8;
  int g = wg / gsize, rem = wg - g * gsize;
  int by = g * 8 + (rem & 7), bx = rem >> 3;
  int m0 = by << 7, n0 = bx << 7;

  int tid = threadIdx.x, lane = tid & 63, wid = tid >> 6;
  int wm = (wid >> 1) << 6, wn = (wid & 1) << 6;

  f32x4 acc[4][4] = {};

  for (int k0 = 0; k0 < K; k0 += 64) {
    __syncthreads();
#pragma unroll
    for (int r = 0; r < 4; ++r) {
      int p = r * 4096 + wid * 1024 + lane * 16;
      int row = p >> 7;
      int cb = (p & 127) ^ ((row & 7) << 4);
      const char* ga = (const char*)A + ((size_t)(m0 + row) * K + k0) * 2 + cb;
      async_cp16(ga, (char*)As + r * 4096 + wid * 1024);
      const char* gb = (const char*)Bt + ((size_t)(n0 + row) * K + k0) * 2 + cb;
      async_cp16(gb, (char*)Bs + r * 4096 + wid * 1024);
    }
    __syncthreads();

#pragma unroll
    for (int ks = 0; ks < 2; ++ks) {
      bf16x8 af[4], bfr[4];
#pragma unroll
      for (int mi = 0; mi < 4; ++mi) {
        int row = wm + mi * 16 + (lane & 15);
        int cb = (ks * 64 + ((lane >> 4) << 4)) ^ ((row & 7) << 4);
        af[mi] = *(const bf16x8*)((const char*)As + row * 128 + cb);
      }
#pragma unroll
      for (int ni = 0; ni < 4; ++ni) {
        int row = wn + ni * 16 + (lane & 15);
        int cb = (ks * 64 + ((lane >> 4) << 4)) ^ ((row & 7) << 4);
        bfr[ni] = *(const bf16x8*)((const char*)Bs + row * 128 + cb);
      }
#pragma unroll
      for (int mi = 0; mi < 4; ++mi)
#pragma unroll
        for (int ni = 0; ni < 4; ++ni)
          acc[mi][ni] = __builtin_amdgcn_mfma_f32_16x16x32_bf16(
              af[mi], bfr[ni], acc[mi][ni], 0, 0, 0);
    }
  }

#pragma unroll
  for (int mi = 0; mi < 4; ++mi)
#pragma unroll
    for (int ni = 0; ni < 4; ++ni)
#pragma unroll
      for (int r = 0; r < 4; ++r) {
        int row = m0 + wm + mi * 16 + ((lane >> 4) << 2) + r;
        int col = n0 + wn + ni * 16 + (lane & 15);
        C[(size_t)row * N + col] = acc[mi][ni][r];
      }
}

// ---------------- causal flash attention (round-8 proven version) -----------
// BQ=128, 16 q-tiles paired (p, 15-p) -> uniform 34 k-tiles per block.
// grid (bh=32, pairp=8): blocks sharing (b,h) -> same XCD -> K/V L2-shared.
// 8 waves x 16 q-rows (2 waves/SIMD TLP). Triple-buffered K/V staging with
// counted vmcnt (wait vmcnt(4) BEFORE raw s_barrier; 2-deep prefetch).
__global__ __launch_bounds__(512, 1)
void attn_kernel(const unsigned short* __restrict__ qh,
                 const unsigned short* __restrict__ kh,
                 const unsigned short* __restrict__ vt,
                 unsigned short* __restrict__ ao) {
  const float SCL2 = 0.08838834764831845f * 1.4426950408889634f;  // scale*log2e
  int bh = blockIdx.x;                       // 0..31
  int pairp = blockIdx.y;                    // 0..7
  int b = bh >> 4, h = bh & 15;

  __shared__ unsigned short Ks[3][64 * 128];   // 3 x 16KB, 256B rows, swizzled
  __shared__ unsigned short Vs[3][128 * 64];   // 3 x 16KB, V^T rows=d, 128B
  __shared__ unsigned short Ps[8][16 * 64];    // 16KB, per-wave P, 128B rows

  int tid = threadIdx.x, lane = tid & 63, wid = tid >> 6;

  const unsigned short* Kg = kh + (size_t)bh * Tc * HD;
  const unsigned short* Vg = vt + (size_t)bh * HD * Tc;

  auto stage = [&](int kt, int buf) {        // 4 vmem loads per thread
#pragma unroll
    for (int r = 0; r < 2; ++r) {
      int p = r * 8192 + wid * 1024 + lane * 16;
      {
        int row = p >> 8, cb = p & 255;
        const char* g = (const char*)Kg + ((size_t)(kt * 64 + row)) * 256 +
                        (cb ^ ((row & 7) << 4));
        async_cp16(g, (char*)&Ks[buf][0] + r * 8192 + wid * 1024);
      }
      {
        int d = p >> 7, cb = p & 127;
        const char* g = (const char*)Vg + (size_t)d * (Tc * 2) + kt * 128 +
                        (cb ^ ((d & 7) << 4));
        async_cp16(g, (char*)&Vs[buf][0] + r * 8192 + wid * 1024);
      }
    }
  };

#pragma unroll 1
  for (int pass = 0; pass < 2; ++pass) {
    int qt = pass ? (15 - pairp) : pairp;
    const unsigned short* Qg = qh + ((size_t)bh * Tc + qt * 128) * HD;

    // Q fragments direct from global; drain so loop vmcnt counts stay exact
    bf16x8 qf[4];
#pragma unroll
    for (int ks = 0; ks < 4; ++ks) {
      int row = wid * 16 + (lane & 15);
      qf[ks] = *(const bf16x8*)((const char*)Qg + row * 256 + ks * 64 +
                                ((lane >> 4) << 4));
    }
    asm volatile("s_waitcnt vmcnt(0)" ::: "memory");

    f32x4 oacc[8] = {};
    float mrow[4], lrow[4];
#pragma unroll
    for (int r = 0; r < 4; ++r) { mrow[r] = -1e30f; lrow[r] = 0.f; }

    int nkt = 2 * (qt + 1);
    __syncthreads();     // pass boundary: prior pass's LDS reads done
    stage(0, 0);
    stage(1, 1);         // nkt >= 2 always
#pragma unroll 1
    for (int kt = 0; kt < nkt; ++kt) {
      // wait for tile kt (own loads), then barrier -> all threads' loads done
      if (kt + 1 < nkt)
        asm volatile("s_waitcnt vmcnt(4)" ::: "memory");
      else
        asm volatile("s_waitcnt vmcnt(0)" ::: "memory");
      asm volatile("s_barrier" ::: "memory");
      if (kt + 2 < nkt) stage(kt + 2, (kt + 2) % 3);
      int cur = kt % 3;

      // S = Q K^T  (16 x 64)
      f32x4 sacc[4] = {};
      __builtin_amdgcn_s_setprio(1);
#pragma unroll
      for (int ks = 0; ks < 4; ++ks) {
#pragma unroll
        for (int ni = 0; ni < 4; ++ni) {
          int row = ni * 16 + (lane & 15);
          int cb = (ks * 64 + ((lane >> 4) << 4)) ^ ((row & 7) << 4);
          bf16x8 kf = *(const bf16x8*)((const char*)&Ks[cur][0] + row * 256 + cb);
          sacc[ni] = __builtin_amdgcn_mfma_f32_16x16x32_bf16(qf[ks], kf,
                                                             sacc[ni], 0, 0, 0);
        }
      }
      __builtin_amdgcn_s_setprio(0);

      // softmax in exp2 domain; defer max & sum (steady path: no cross-lane)
      bool diag = (kt >= 2 * qt);
      float sv[4][4];              // [ni][r]
      float pmax[4];
      bool allok = true;
#pragma unroll
      for (int r = 0; r < 4; ++r) {
        int qrow = qt * 128 + wid * 16 + ((lane >> 4) << 2) + r;
        float mx = -1e30f;
#pragma unroll
        for (int ni = 0; ni < 4; ++ni) {
          float s = sacc[ni][r] * SCL2;
          if (diag) {
            int kcol = kt * 64 + ni * 16 + (lane & 15);
            if (kcol > qrow) s = -1e30f;
          }
          sv[ni][r] = s;
          mx = fmaxf(mx, s);
        }
        pmax[r] = mx;
        allok = allok && (mx <= mrow[r] + 8.f);
      }
      if (!__all(allok)) {         // rare: running max moved -> reduce+rescale
#pragma unroll
        for (int r = 0; r < 4; ++r) {
          float gm = pmax[r];
          gm = fmaxf(gm, __shfl_xor(gm, 1));
          gm = fmaxf(gm, __shfl_xor(gm, 2));
          gm = fmaxf(gm, __shfl_xor(gm, 4));
          gm = fmaxf(gm, __shfl_xor(gm, 8));
          float mnew = fmaxf(mrow[r], gm);
          float fsc = exp2f(mrow[r] - mnew);
          mrow[r] = mnew;
          lrow[r] *= fsc;
#pragma unroll
          for (int nj = 0; nj < 8; ++nj) oacc[nj][r] *= fsc;
        }
      }

      // P = exp2(sv - m); per-lane partial sums; write P (bf16) to LDS
#pragma unroll
      for (int ni = 0; ni < 4; ++ni)
#pragma unroll
        for (int r = 0; r < 4; ++r) {
          float pp = exp2f(sv[ni][r] - mrow[r]);
          lrow[r] += pp;
          int row = ((lane >> 4) << 2) + r;
          int colb = (ni * 16 + (lane & 15)) * 2;
          *(unsigned short*)((char*)&Ps[wid][0] + row * 128 +
                             (colb ^ ((row & 7) << 4))) = f2bf(pp);
        }

      // O += P @ V  (same-wave LDS RAW; compiler inserts lgkmcnt waits)
      __builtin_amdgcn_s_setprio(1);
#pragma unroll
      for (int ks = 0; ks < 2; ++ks) {
        int prow = lane & 15;
        int pcb = (ks * 64 + ((lane >> 4) << 4)) ^ ((prow & 7) << 4);
        bf16x8 pf = *(const bf16x8*)((const char*)&Ps[wid][0] + prow * 128 + pcb);
#pragma unroll
        for (int nj = 0; nj < 8; ++nj) {
          int vrow = nj * 16 + (lane & 15);
          int vcb = (ks * 64 + ((lane >> 4) << 4)) ^ ((vrow & 7) << 4);
          bf16x8 vf = *(const bf16x8*)((const char*)&Vs[cur][0] + vrow * 128 + vcb);
          oacc[nj] = __builtin_amdgcn_mfma_f32_16x16x32_bf16(pf, vf,
                                                             oacc[nj], 0, 0, 0);
        }
      }
      __builtin_amdgcn_s_setprio(0);
    }

    // epilogue: reduce deferred row sums across 16-lane groups, normalize
    float inv[4];
#pragma unroll
    for (int r = 0; r < 4; ++r) {
      float s = lrow[r];
      s += __shfl_xor(s, 1);
      s += __shfl_xor(s, 2);
      s += __shfl_xor(s, 4);
      s += __shfl_xor(s, 8);
      inv[r] = 1.f / s;
    }
#pragma unroll
    for (int nj = 0; nj < 8; ++nj)
#pragma unroll
      for (int r = 0; r < 4; ++r) {
        int trow = qt * 128 + wid * 16 + ((lane >> 4) << 2) + r;
        int col = nj * 16 + (lane & 15);
        ao[((size_t)(b * Tc + trow)) * Dc + h * HD + col] =
            f2bf(oacc[nj][r] * inv[r]);
      }
  }
}

// ---------------- launcher --------------------------------------------------
extern "C" void kernel_launch(void* const* d_in, const int* in_sizes, int n_in,
                              void* d_out, int out_size, void* d_ws,
                              size_t ws_size, hipStream_t stream) {
  const float* x = (const float*)d_in[0];
  const float* w_qkv = (const float*)d_in[1];
  const float* w_out = (const float*)d_in[2];
  float* out = (float*)d_out;

  char* ws = (char*)d_ws;
  size_t off = 0;
  auto alloc = [&](size_t bytes) {
    char* p = ws + off;
    off += (bytes + 255) & ~(size_t)255;
    return p;
  };
  unsigned short* xb    = (unsigned short*)alloc((size_t)MR * Dc * 2);
  unsigned short* wqkvT = (unsigned short*)alloc((size_t)NQKV * Dc * 2);
  unsigned short* woutT = (unsigned short*)alloc((size_t)Dc * Dc * 2);
  unsigned short* qhp   = (unsigned short*)alloc((size_t)MR * Dc * 2);
  unsigned short* khp   = (unsigned short*)alloc((size_t)MR * Dc * 2);
  unsigned short* vtp   = (unsigned short*)alloc((size_t)MR * Dc * 2);
  unsigned short* aop   = (unsigned short*)alloc((size_t)MR * Dc * 2);
  float2* cs            = (float2*)alloc((size_t)Tc * 64 * sizeof(float2));

  rope_table_kernel<<<Tc, 64, 0, stream>>>(cs);
  f32_to_bf16_kernel<<<(MR * Dc / 4 + 255) / 256, 256, 0, stream>>>(x, xb, MR * Dc);
  transpose_f32_bf16_kernel<<<dim3(NQKV / 64, Dc / 64), 256, 0, stream>>>(
      w_qkv, wqkvT, Dc, NQKV);
  transpose_f32_bf16_kernel<<<dim3(Dc / 64, Dc / 64), 256, 0, stream>>>(
      w_out, woutT, Dc, Dc);
  gemm_qkv_kernel<<<(MR / 128) * (NQKV / 128), 256, 0, stream>>>(
      xb, wqkvT, cs, qhp, khp, vtp);
  attn_kernel<<<dim3(32, 8), 512, 0, stream>>>(qhp, khp, vtp, aop);
  gemm_bt_kernel<<<(MR / 128) * (Dc / 128), 256, 0, stream>>>(
      aop, woutT, out, MR, Dc, Dc);
}